// Round 1
// baseline (2256.858 us; speedup 1.0000x reference)
//
#include <hip/hip_runtime.h>
#include <hip/hip_bf16.h>
#include <stdint.h>

// Problem: T=128, B=32, D=1024, H=1024 LSTM unroll, fp32 in/out.
#define T_STEPS 128
#define BATCH   32
#define DIM     1024
#define HID     1024
#define NGATE   4096            // 4*H
#define MROWS   4096            // T*B
#define NWG     256             // persistent workgroups (1 per CU)

typedef unsigned int u32;
typedef __attribute__((ext_vector_type(8))) __bf16 bf16x8;
typedef __attribute__((ext_vector_type(4))) float  f32x4;
typedef __attribute__((ext_vector_type(4))) u32    u32x4;

__device__ __forceinline__ unsigned short f2bf(float f) {
    u32 x = __float_as_uint(f);
    return (unsigned short)((x + 0x7fffu + ((x >> 16) & 1u)) >> 16);  // RNE
}
__device__ __forceinline__ float sigf(float x) {
    return 1.0f / (1.0f + __expf(-x));
}
__device__ __forceinline__ float tanh_fast(float x) {
    float ax = fabsf(x);
    float e  = __expf(-2.0f * ax);           // in (0,1], no overflow
    float t  = (1.0f - e) / (1.0f + e);
    return copysignf(t, x);
}

// ---------------- prep kernels ----------------

__global__ void cast_f32_bf16(const float* __restrict__ in,
                              unsigned short* __restrict__ out, int n) {
    int idx = (blockIdx.x * blockDim.x + threadIdx.x) * 4;
    if (idx + 3 < n) {
        float4 v = *(const float4*)(in + idx);
        ushort4 o;
        o.x = f2bf(v.x); o.y = f2bf(v.y); o.z = f2bf(v.z); o.w = f2bf(v.w);
        *(ushort4*)(out + idx) = o;
    }
}

__global__ void zero_u32(u32* __restrict__ p, int n) {
    int i = blockIdx.x * blockDim.x + threadIdx.x;
    if (i < n) p[i] = 0u;
}

// in: R x C fp32 (row-major) -> out: C x R bf16 (row-major transpose)
__global__ void transpose_cast(const float* __restrict__ in,
                               unsigned short* __restrict__ out, int R, int C) {
    __shared__ float tile[32][33];
    int c0 = blockIdx.x * 32, r0 = blockIdx.y * 32;
    int tx = threadIdx.x, ty = threadIdx.y;     // 32 x 8
#pragma unroll
    for (int i = 0; i < 4; ++i)
        tile[ty + i * 8][tx] = in[(size_t)(r0 + ty + i * 8) * C + c0 + tx];
    __syncthreads();
#pragma unroll
    for (int i = 0; i < 4; ++i)
        out[(size_t)(c0 + ty + i * 8) * R + r0 + tx] = f2bf(tile[tx][ty + i * 8]);
}

// ---------------- phase 1: G = x @ Wx + b  (bf16 MFMA, fp32 out) ----------------
// A: MROWS x DIM bf16 (x), BT: NGATE x DIM bf16 (WxT), G: MROWS x NGATE fp32.
// 128x128 tile, BK=32, 256 threads = 4 waves in 2x2, each wave 64x64 (4x4 MFMA tiles).
__global__ __launch_bounds__(256) void gemm_xw(
    const unsigned short* __restrict__ A,
    const unsigned short* __restrict__ BT,
    const float* __restrict__ bias,
    float* __restrict__ G) {
    __shared__ unsigned short As[128 * 32];
    __shared__ unsigned short Bs[128 * 32];
    int tid  = threadIdx.x;
    int wave = tid >> 6, lane = tid & 63;
    int q = lane >> 4, c = lane & 15;
    int wm = wave >> 1, wn = wave & 1;
    int tm = blockIdx.y * 128, tn = blockIdx.x * 128;

    f32x4 acc[4][4] = {};

    const int srow0 = tid >> 2;           // 0..63
    const int srow1 = 64 + (tid >> 2);    // 64..127
    const int scol  = (tid & 3) * 8;      // bf16 elems

    u32x4 ra0, ra1, rb0, rb1;
    ra0 = *(const u32x4*)(A  + (size_t)(tm + srow0) * DIM + scol);
    ra1 = *(const u32x4*)(A  + (size_t)(tm + srow1) * DIM + scol);
    rb0 = *(const u32x4*)(BT + (size_t)(tn + srow0) * DIM + scol);
    rb1 = *(const u32x4*)(BT + (size_t)(tn + srow1) * DIM + scol);

    for (int kk = 0; kk < 32; ++kk) {
        __syncthreads();   // previous iteration's compute done -> LDS reusable
        *(u32x4*)(As + srow0 * 32 + scol) = ra0;
        *(u32x4*)(As + srow1 * 32 + scol) = ra1;
        *(u32x4*)(Bs + srow0 * 32 + scol) = rb0;
        *(u32x4*)(Bs + srow1 * 32 + scol) = rb1;
        __syncthreads();
        if (kk < 31) {   // prefetch next K-slab while computing this one
            int ko = (kk + 1) * 32 + scol;
            ra0 = *(const u32x4*)(A  + (size_t)(tm + srow0) * DIM + ko);
            ra1 = *(const u32x4*)(A  + (size_t)(tm + srow1) * DIM + ko);
            rb0 = *(const u32x4*)(BT + (size_t)(tn + srow0) * DIM + ko);
            rb1 = *(const u32x4*)(BT + (size_t)(tn + srow1) * DIM + ko);
        }
        bf16x8 af[4], bfv[4];
#pragma unroll
        for (int i = 0; i < 4; ++i) {
            af[i]  = *(const bf16x8*)(As + (wm * 64 + i * 16 + c) * 32 + q * 8);
            bfv[i] = *(const bf16x8*)(Bs + (wn * 64 + i * 16 + c) * 32 + q * 8);
        }
#pragma unroll
        for (int i = 0; i < 4; ++i)
#pragma unroll
            for (int j = 0; j < 4; ++j)
                acc[i][j] = __builtin_amdgcn_mfma_f32_16x16x32_bf16(
                    af[i], bfv[j], acc[i][j], 0, 0, 0);
    }
    // epilogue: C/D layout col = lane&15, row = quad*4 + reg
#pragma unroll
    for (int j = 0; j < 4; ++j) {
        int col = tn + wn * 64 + j * 16 + c;
        float bj = bias[col];
#pragma unroll
        for (int i = 0; i < 4; ++i) {
            int row0 = tm + wm * 64 + i * 16 + q * 4;
#pragma unroll
            for (int r = 0; r < 4; ++r)
                G[(size_t)(row0 + r) * NGATE + col] = acc[i][j][r] + bj;
        }
    }
}

// ---------------- phase 2: persistent weight-stationary recurrence ----------------
// 256 WGs x 128 threads. WG wg owns hidden units [wg*4, wg*4+4): 16 gate columns
// (order: gate-major, col c -> gate g=c>>2, unit u=c&3; global col g*H + wg*4 + u).
// WhT rows for those columns live in LDS for all 128 steps. Per step:
//   gates(32x16) = G_t(slice) + h_t(32x1024) @ WhT_tile^T  via 16x16x32 bf16 MFMA,
//   wave w handles batches [w*16, w*16+16). h broadcast via per-step global buffers
//   (write-once addresses) + per-WG flags (relaxed agent polls, one acquire fence).
__global__ __launch_bounds__(128) void lstm_rec(
    const unsigned short* __restrict__ WhT,   // NGATE x DIM bf16
    const float* __restrict__ G,              // MROWS x NGATE fp32
    unsigned short* __restrict__ hb,          // (T+1) x BATCH x HID bf16
    u32* flags,                               // (T+1) x NWG
    float* __restrict__ out) {                // T x BATCH x HID fp32
    __shared__ unsigned short Wl[16 * 1032];  // 16 rows x (1024+8 pad) bf16 = 33 KB
    const int wg   = blockIdx.x;
    const int tid  = threadIdx.x;
    const int wave = tid >> 6, lane = tid & 63;
    const int q = lane >> 4, c = lane & 15;
    const int u = c & 3, g = c >> 2;

    // stage this WG's 16 WhT rows into LDS (once)
    for (int i = tid; i < 16 * 128; i += 128) {
        int row = i >> 7, chunk = i & 127;
        int grow = (row >> 2) * HID + wg * 4 + (row & 3);
        *(u32x4*)(Wl + row * 1032 + chunk * 8) =
            *(const u32x4*)(WhT + (size_t)grow * DIM + chunk * 8);
    }
    __syncthreads();

    float cs[4] = {0.f, 0.f, 0.f, 0.f};       // c-state, fp32, owner lanes (g==0)
    const int gcol = g * HID + wg * 4 + u;

    for (int t = 0; t < T_STEPS; ++t) {
        if (t > 0) {
            u32* fl = flags + t * NWG;
            while (__hip_atomic_load(&fl[tid], __ATOMIC_RELAXED,
                                     __HIP_MEMORY_SCOPE_AGENT) == 0u) {}
            while (__hip_atomic_load(&fl[tid + 128], __ATOMIC_RELAXED,
                                     __HIP_MEMORY_SCOPE_AGENT) == 0u) {}
            __builtin_amdgcn_fence(__ATOMIC_ACQUIRE, "agent");
            __syncthreads();   // collectively: all 256 flags seen, caches inv'd
        }

        // init accumulators from G_t (fp32) -- D layout: col=c, row=q*4+r
        f32x4 acc0, acc1;
#pragma unroll
        for (int r = 0; r < 4; ++r) {
            int row = t * BATCH + wave * 16 + q * 4 + r;
            acc0[r] = G[(size_t)row * NGATE + gcol];
            acc1[r] = 0.f;
        }

        const unsigned short* hrow = hb + (size_t)t * BATCH * HID;
#pragma unroll
        for (int kk = 0; kk < 32; ++kk) {
            bf16x8 a = *(const bf16x8*)(hrow + (size_t)(wave * 16 + c) * HID
                                        + kk * 32 + q * 8);
            bf16x8 b = *(const bf16x8*)(Wl + c * 1032 + kk * 32 + q * 8);
            if (kk & 1)
                acc1 = __builtin_amdgcn_mfma_f32_16x16x32_bf16(a, b, acc1, 0, 0, 0);
            else
                acc0 = __builtin_amdgcn_mfma_f32_16x16x32_bf16(a, b, acc0, 0, 0, 0);
        }

        f32x4 gates;
#pragma unroll
        for (int r = 0; r < 4; ++r) gates[r] = acc0[r] + acc1[r];

        // gather 4 gates per (batch, unit) via shuffles within the quad's 16 lanes
        const int base = lane & ~15;
#pragma unroll
        for (int r = 0; r < 4; ++r) {
            float iv = __shfl(gates[r], base + u,      64);
            float fv = __shfl(gates[r], base + 4 + u,  64);
            float gv = __shfl(gates[r], base + 8 + u,  64);
            float ov = __shfl(gates[r], base + 12 + u, 64);
            if (g == 0) {  // owner lanes: cols 0..3
                float cn = sigf(fv) * cs[r] + sigf(iv) * tanh_fast(gv);
                cs[r] = cn;
                float hv = sigf(ov) * tanh_fast(cn);
                int batch = wave * 16 + q * 4 + r;
                int hu = wg * 4 + u;
                out[((size_t)t * BATCH + batch) * HID + hu] = hv;
                hb[(size_t)(t + 1) * BATCH * HID + (size_t)batch * HID + hu] = f2bf(hv);
            }
        }

        __syncthreads();   // drains vmcnt: all h stores of this WG complete
        if (tid == 0) {
            __builtin_amdgcn_fence(__ATOMIC_RELEASE, "agent");  // L2 writeback
            __hip_atomic_store(flags + (t + 1) * NWG + wg, 1u,
                               __ATOMIC_RELAXED, __HIP_MEMORY_SCOPE_AGENT);
        }
    }
}

// ---------------- launch ----------------

extern "C" void kernel_launch(void* const* d_in, const int* in_sizes, int n_in,
                              void* d_out, int out_size, void* d_ws, size_t ws_size,
                              hipStream_t stream) {
    const float* x  = (const float*)d_in[0];   // T*B*D
    const float* Wx = (const float*)d_in[1];   // D x 4H
    const float* Wh = (const float*)d_in[2];   // H x 4H
    const float* b  = (const float*)d_in[3];   // 4H
    float* out = (float*)d_out;

    // workspace layout (bytes)
    char* ws = (char*)d_ws;
    const size_t OFF_XBF  = 0;                       // 8 MB  (4096x1024 bf16)
    const size_t OFF_WXT  = 8ull  << 20;             // 8 MB  (4096x1024 bf16)
    const size_t OFF_WHT  = 16ull << 20;             // 8 MB  (4096x1024 bf16)
    const size_t OFF_G    = 24ull << 20;             // 64 MB (4096x4096 fp32)
    const size_t OFF_HB   = 88ull << 20;             // 129 * 64 KB = 8.0625 MB
    const size_t OFF_FLAG = 97ull << 20;             // 129 * 256 * 4 B
    const size_t NEEDED   = OFF_FLAG + (size_t)(T_STEPS + 1) * NWG * 4;
    if (ws_size < NEEDED) return;  // loud failure (output stays poisoned)

    unsigned short* xbf = (unsigned short*)(ws + OFF_XBF);
    unsigned short* WxT = (unsigned short*)(ws + OFF_WXT);
    unsigned short* WhT = (unsigned short*)(ws + OFF_WHT);
    float*          G   = (float*)(ws + OFF_G);
    unsigned short* hb  = (unsigned short*)(ws + OFF_HB);
    u32*            fl  = (u32*)(ws + OFF_FLAG);

    // prep
    cast_f32_bf16<<<(MROWS * DIM / 4 + 255) / 256, 256, 0, stream>>>(x, xbf, MROWS * DIM);
    zero_u32<<<(BATCH * HID / 2 + 255) / 256, 256, 0, stream>>>((u32*)hb, BATCH * HID / 2);
    int nflags = (T_STEPS + 1) * NWG;
    zero_u32<<<(nflags + 255) / 256, 256, 0, stream>>>(fl, nflags);
    dim3 tb(32, 8);
    transpose_cast<<<dim3(NGATE / 32, DIM / 32), tb, 0, stream>>>(Wx, WxT, DIM, NGATE);
    transpose_cast<<<dim3(NGATE / 32, HID / 32), tb, 0, stream>>>(Wh, WhT, HID, NGATE);

    // phase 1: all-timestep input GEMM
    gemm_xw<<<dim3(NGATE / 128, MROWS / 128), 256, 0, stream>>>(xbf, WxT, b, G);

    // phase 2: persistent recurrence
    lstm_rec<<<NWG, 128, 0, stream>>>(WhT, G, hb, fl, out);
}

// Round 2
// 1240.174 us; speedup vs baseline: 1.8198x; 1.8198x over previous
//
#include <hip/hip_runtime.h>
#include <hip/hip_bf16.h>
#include <stdint.h>

// Problem: T=128, B=32, D=1024, H=1024 LSTM unroll, fp32 in/out.
#define T_STEPS 128
#define BATCH   32
#define DIM     1024
#define HID     1024
#define NGATE   4096            // 4*H
#define MROWS   4096            // T*B
#define NWGR    32              // persistent recurrence workgroups

typedef unsigned int u32;
typedef __attribute__((ext_vector_type(8)))  __bf16 bf16x8;
typedef __attribute__((ext_vector_type(4)))  float  f32x4;
typedef __attribute__((ext_vector_type(16))) float  f32x16;
typedef __attribute__((ext_vector_type(4)))  u32    u32x4;

__device__ __forceinline__ unsigned short f2bf(float f) {
    u32 x = __float_as_uint(f);
    return (unsigned short)((x + 0x7fffu + ((x >> 16) & 1u)) >> 16);  // RNE
}
__device__ __forceinline__ float sigf(float x) {
    return 1.0f / (1.0f + __expf(-x));
}
__device__ __forceinline__ float tanh_fast(float x) {
    float ax = fabsf(x);
    float e  = __expf(-2.0f * ax);           // in (0,1], no overflow
    float t  = (1.0f - e) / (1.0f + e);
    return copysignf(t, x);
}

// ---------------- prep kernels ----------------

__global__ void cast_f32_bf16(const float* __restrict__ in,
                              unsigned short* __restrict__ out, int n) {
    int idx = (blockIdx.x * blockDim.x + threadIdx.x) * 4;
    if (idx + 3 < n) {
        float4 v = *(const float4*)(in + idx);
        ushort4 o;
        o.x = f2bf(v.x); o.y = f2bf(v.y); o.z = f2bf(v.z); o.w = f2bf(v.w);
        *(ushort4*)(out + idx) = o;
    }
}

__global__ void zero_u32(u32* __restrict__ p, int n) {
    int i = blockIdx.x * blockDim.x + threadIdx.x;
    if (i < n) p[i] = 0u;
}

// in: R x C fp32 (row-major) -> out: C x R bf16 (row-major transpose)
__global__ void transpose_cast(const float* __restrict__ in,
                               unsigned short* __restrict__ out, int R, int C) {
    __shared__ float tile[32][33];
    int c0 = blockIdx.x * 32, r0 = blockIdx.y * 32;
    int tx = threadIdx.x, ty = threadIdx.y;     // 32 x 8
#pragma unroll
    for (int i = 0; i < 4; ++i)
        tile[ty + i * 8][tx] = in[(size_t)(r0 + ty + i * 8) * C + c0 + tx];
    __syncthreads();
#pragma unroll
    for (int i = 0; i < 4; ++i)
        out[(size_t)(c0 + ty + i * 8) * R + r0 + tx] = f2bf(tile[tx][ty + i * 8]);
}

// ---------------- phase 1: Gp = perm(x @ Wx + b)  (bf16 MFMA, fp32 out) ----------------
// A: MROWS x DIM bf16 (x), BT: NGATE x DIM bf16 (WxT).
// Output written in recurrence-friendly permuted panels:
//   orig col co = g*1024 + hu  ->  panel wg = hu>>5, local col cp = g*32 + (hu&31)
//   Gp[((wg*MROWS)+row)*128 + cp]
__global__ __launch_bounds__(256) void gemm_xw(
    const unsigned short* __restrict__ A,
    const unsigned short* __restrict__ BT,
    const float* __restrict__ bias,
    float* __restrict__ Gp) {
    __shared__ unsigned short As[128 * 32];
    __shared__ unsigned short Bs[128 * 32];
    int tid  = threadIdx.x;
    int wave = tid >> 6, lane = tid & 63;
    int q = lane >> 4, c = lane & 15;
    int wm = wave >> 1, wn = wave & 1;
    int tm = blockIdx.y * 128, tn = blockIdx.x * 128;

    f32x4 acc[4][4] = {};

    const int srow0 = tid >> 2;           // 0..63
    const int srow1 = 64 + (tid >> 2);    // 64..127
    const int scol  = (tid & 3) * 8;      // bf16 elems

    u32x4 ra0, ra1, rb0, rb1;
    ra0 = *(const u32x4*)(A  + (size_t)(tm + srow0) * DIM + scol);
    ra1 = *(const u32x4*)(A  + (size_t)(tm + srow1) * DIM + scol);
    rb0 = *(const u32x4*)(BT + (size_t)(tn + srow0) * DIM + scol);
    rb1 = *(const u32x4*)(BT + (size_t)(tn + srow1) * DIM + scol);

    for (int kk = 0; kk < 32; ++kk) {
        __syncthreads();
        *(u32x4*)(As + srow0 * 32 + scol) = ra0;
        *(u32x4*)(As + srow1 * 32 + scol) = ra1;
        *(u32x4*)(Bs + srow0 * 32 + scol) = rb0;
        *(u32x4*)(Bs + srow1 * 32 + scol) = rb1;
        __syncthreads();
        if (kk < 31) {
            int ko = (kk + 1) * 32 + scol;
            ra0 = *(const u32x4*)(A  + (size_t)(tm + srow0) * DIM + ko);
            ra1 = *(const u32x4*)(A  + (size_t)(tm + srow1) * DIM + ko);
            rb0 = *(const u32x4*)(BT + (size_t)(tn + srow0) * DIM + ko);
            rb1 = *(const u32x4*)(BT + (size_t)(tn + srow1) * DIM + ko);
        }
        bf16x8 af[4], bfv[4];
#pragma unroll
        for (int i = 0; i < 4; ++i) {
            af[i]  = *(const bf16x8*)(As + (wm * 64 + i * 16 + c) * 32 + q * 8);
            bfv[i] = *(const bf16x8*)(Bs + (wn * 64 + i * 16 + c) * 32 + q * 8);
        }
#pragma unroll
        for (int i = 0; i < 4; ++i)
#pragma unroll
            for (int j = 0; j < 4; ++j)
                acc[i][j] = __builtin_amdgcn_mfma_f32_16x16x32_bf16(
                    af[i], bfv[j], acc[i][j], 0, 0, 0);
    }
    // epilogue: C/D layout col = lane&15, row = quad*4 + reg; permuted store
#pragma unroll
    for (int j = 0; j < 4; ++j) {
        int co = tn + wn * 64 + j * 16 + c;
        float bj = bias[co];
        int g = co >> 10, hu = co & 1023;
        int wgr = hu >> 5, u = hu & 31;
        int cp = g * 32 + u;
#pragma unroll
        for (int i = 0; i < 4; ++i) {
            int row0 = tm + wm * 64 + i * 16 + q * 4;
#pragma unroll
            for (int r = 0; r < 4; ++r)
                Gp[((size_t)wgr * MROWS + row0 + r) * 128 + cp] = acc[i][j][r] + bj;
        }
    }
}

// ---------------- phase 2: persistent recurrence, weights in registers ----------------
// 32 WGs x 512 threads (8 waves). WG wg owns hidden units [wg*32, wg*32+32) -> 128
// permuted gate cols. Wave wv: cg = wv&1 (col half, 64 cols as 2x 32-col tiles),
// ks = wv>>1 (K-split, 256 of 1024). B-fragments (Wh) live in 128 VGPRs/lane for all
// 128 steps. Per step: A (h_t) read straight from LLC (global), 32x32x16 MFMAs,
// 4 K-split partials summed via LDS, cell update, h broadcast via system-scope
// write-through stores + per-WG flags. No release fence -> no buffer_wbl2.
__global__ __launch_bounds__(512, 2) void lstm_rec(
    const unsigned short* __restrict__ WhT,   // NGATE x DIM bf16
    const float* __restrict__ Gp,             // permuted gates, 32 x 4096 x 128 fp32
    unsigned short* hb,                       // (T+1) x BATCH x HID bf16 (slot 0 unused)
    u32* flags,                               // (T+1) x NWGR
    float* __restrict__ out) {                // T x BATCH x HID fp32
    __shared__ float Gl[2][32][132];          // double-buffered G slice (padded)
    __shared__ float SlT[4][128][36];         // K-split partials, transposed (padded)
    const int wg = blockIdx.x, tid = threadIdx.x;
    const int wv = tid >> 6, lane = tid & 63;
    const int cg = wv & 1, ks = wv >> 1;
    const int ln = lane & 31, lh = lane >> 5;

    // ---- stage B-fragments (Wh) into registers, once ----
    bf16x8 br0[16], br1[16];
    {
        const unsigned short* w0 =
            WhT + (size_t)((cg * 2 + 0) * HID + wg * 32 + ln) * DIM + ks * 256 + lh * 8;
        const unsigned short* w1 =
            WhT + (size_t)((cg * 2 + 1) * HID + wg * 32 + ln) * DIM + ks * 256 + lh * 8;
#pragma unroll
        for (int kk = 0; kk < 16; ++kk) {
            br0[kk] = *(const bf16x8*)(w0 + kk * 16);
            br1[kk] = *(const bf16x8*)(w1 + kk * 16);
        }
    }

    // ---- G slice for t=0 into Gl[0] ----
    {
        const float* p = Gp + (size_t)wg * MROWS * 128 + tid * 8;
        f32x4 a = *(const f32x4*)p, b2 = *(const f32x4*)(p + 4);
        float* d = &Gl[0][tid >> 4][(tid & 15) * 8];
        *(f32x4*)d = a; *(f32x4*)(d + 4) = b2;
    }
    __syncthreads();

    const int batch = tid >> 4, uu = tid & 15;
    float cs0 = 0.f, cs1 = 0.f;

    for (int t = 0; t < T_STEPS; ++t) {
        const int cur = t & 1, nxt = (t + 1) & 1;
        if (t > 0) {
            if (tid < NWGR) {
                const u32* fp = flags + (size_t)t * NWGR + tid;
                while (__hip_atomic_load(fp, __ATOMIC_RELAXED,
                                         __HIP_MEMORY_SCOPE_SYSTEM) == 0u) {}
            }
            __syncthreads();
            __builtin_amdgcn_fence(__ATOMIC_ACQUIRE, "agent");   // buffer_inv only
        }

        // prefetch next step's G slice (independent of recurrence)
        f32x4 ga = {}, gb = {};
        if (t + 1 < T_STEPS) {
            const float* p = Gp + ((size_t)wg * MROWS + (size_t)(t + 1) * 32) * 128 + tid * 8;
            ga = *(const f32x4*)p;
            gb = *(const f32x4*)(p + 4);
        }

        // ---- h_t @ Wh partial: 32 MFMAs per wave, A from global (LLC), B from regs ----
        f32x16 acc0 = {}, acc1 = {};
        if (t > 0) {
            const unsigned short* hrow = hb + (size_t)t * (BATCH * HID)
                                       + (size_t)ln * HID + ks * 256 + lh * 8;
#pragma unroll
            for (int kk = 0; kk < 16; ++kk) {
                bf16x8 a = *(const bf16x8*)(hrow + kk * 16);
                acc0 = __builtin_amdgcn_mfma_f32_32x32x16_bf16(a, br0[kk], acc0, 0, 0, 0);
                acc1 = __builtin_amdgcn_mfma_f32_32x32x16_bf16(a, br1[kk], acc1, 0, 0, 0);
            }
        }

        // write K-split partials, transposed: row = rr + 8*rg + 4*lh, col = lane col
#pragma unroll
        for (int rg = 0; rg < 4; ++rg) {
            f32x4 v0, v1;
#pragma unroll
            for (int rr = 0; rr < 4; ++rr) { v0[rr] = acc0[rg * 4 + rr];
                                             v1[rr] = acc1[rg * 4 + rr]; }
            *(f32x4*)&SlT[ks][cg * 64 + ln]      [rg * 8 + lh * 4] = v0;
            *(f32x4*)&SlT[ks][cg * 64 + 32 + ln] [rg * 8 + lh * 4] = v1;
        }
        if (t + 1 < T_STEPS) {
            float* d = &Gl[nxt][tid >> 4][(tid & 15) * 8];
            *(f32x4*)d = ga; *(f32x4*)(d + 4) = gb;
        }
        __syncthreads();

        // ---- epilogue: thread = (batch, uu), units uu and uu+16 ----
#pragma unroll
        for (int ui = 0; ui < 2; ++ui) {
            const int u = uu + ui * 16;
            float gv[4];
#pragma unroll
            for (int g = 0; g < 4; ++g) {
                const int cp = g * 32 + u;
                gv[g] = Gl[cur][batch][cp]
                      + SlT[0][cp][batch] + SlT[1][cp][batch]
                      + SlT[2][cp][batch] + SlT[3][cp][batch];
            }
            float cprev = ui ? cs1 : cs0;
            float cn = sigf(gv[1]) * cprev + sigf(gv[0]) * tanh_fast(gv[2]);
            if (ui) cs1 = cn; else cs0 = cn;
            float hv = sigf(gv[3]) * tanh_fast(cn);
            out[((size_t)t * BATCH + batch) * HID + wg * 32 + u] = hv;
            // write-through to LLC (sc0/sc1) -> visible once vmcnt-retired
            __hip_atomic_store(hb + (size_t)(t + 1) * (BATCH * HID)
                                  + (size_t)batch * HID + wg * 32 + u,
                               f2bf(hv), __ATOMIC_RELAXED, __HIP_MEMORY_SCOPE_SYSTEM);
        }

        // all h stores of every thread ack'd at LLC before flag goes up
        asm volatile("s_waitcnt vmcnt(0)" ::: "memory");
        __syncthreads();
        if (tid == 0)
            __hip_atomic_store(flags + (size_t)(t + 1) * NWGR + wg, 1u,
                               __ATOMIC_RELAXED, __HIP_MEMORY_SCOPE_SYSTEM);
    }
}

// ---------------- launch ----------------

extern "C" void kernel_launch(void* const* d_in, const int* in_sizes, int n_in,
                              void* d_out, int out_size, void* d_ws, size_t ws_size,
                              hipStream_t stream) {
    const float* x  = (const float*)d_in[0];   // T*B*D
    const float* Wx = (const float*)d_in[1];   // D x 4H
    const float* Wh = (const float*)d_in[2];   // H x 4H
    const float* b  = (const float*)d_in[3];   // 4H
    float* out = (float*)d_out;

    // workspace layout (bytes)
    char* ws = (char*)d_ws;
    const size_t OFF_XBF  = 0;                       // 8 MB  (4096x1024 bf16)
    const size_t OFF_WXT  = 8ull  << 20;             // 8 MB  (4096x1024 bf16)
    const size_t OFF_WHT  = 16ull << 20;             // 8 MB  (4096x1024 bf16)
    const size_t OFF_G    = 24ull << 20;             // 64 MB (32x4096x128 fp32 permuted)
    const size_t OFF_HB   = 88ull << 20;             // 129 * 64 KB = 8.0625 MB
    const size_t OFF_FLAG = 97ull << 20;             // 129 * 32 * 4 B
    const size_t NEEDED   = OFF_FLAG + (size_t)(T_STEPS + 1) * NWGR * 4;
    if (ws_size < NEEDED) return;  // loud failure (output stays poisoned)

    unsigned short* xbf = (unsigned short*)(ws + OFF_XBF);
    unsigned short* WxT = (unsigned short*)(ws + OFF_WXT);
    unsigned short* WhT = (unsigned short*)(ws + OFF_WHT);
    float*          Gp  = (float*)(ws + OFF_G);
    unsigned short* hb  = (unsigned short*)(ws + OFF_HB);
    u32*            fl  = (u32*)(ws + OFF_FLAG);

    // prep
    cast_f32_bf16<<<(MROWS * DIM / 4 + 255) / 256, 256, 0, stream>>>(x, xbf, MROWS * DIM);
    int nflags = (T_STEPS + 1) * NWGR;
    zero_u32<<<(nflags + 255) / 256, 256, 0, stream>>>(fl, nflags);
    dim3 tb(32, 8);
    transpose_cast<<<dim3(NGATE / 32, DIM / 32), tb, 0, stream>>>(Wx, WxT, DIM, NGATE);
    transpose_cast<<<dim3(NGATE / 32, HID / 32), tb, 0, stream>>>(Wh, WhT, HID, NGATE);

    // phase 1: all-timestep input GEMM (permuted output)
    gemm_xw<<<dim3(NGATE / 128, MROWS / 128), 256, 0, stream>>>(xbf, WxT, b, Gp);

    // phase 2: persistent recurrence
    lstm_rec<<<NWGR, 512, 0, stream>>>(WhT, Gp, hb, fl, out);
}

// Round 4
// 1038.709 us; speedup vs baseline: 2.1728x; 1.1940x over previous
//
#include <hip/hip_runtime.h>
#include <hip/hip_bf16.h>
#include <stdint.h>

// Problem: T=128, B=32, D=1024, H=1024 LSTM unroll, fp32 in/out.
#define T_STEPS 128
#define BATCH   32
#define DIM     1024
#define HID     1024
#define NGATE   4096            // 4*H
#define MROWS   4096            // T*B
#define NWGR    32              // persistent recurrence workgroups

typedef unsigned int u32;
typedef __attribute__((ext_vector_type(8)))  __bf16 bf16x8;
typedef __attribute__((ext_vector_type(4)))  float  f32x4;
typedef __attribute__((ext_vector_type(16))) float  f32x16;
typedef __attribute__((ext_vector_type(4)))  u32    u32x4;

__device__ __forceinline__ unsigned short f2bf(float f) {
    u32 x = __float_as_uint(f);
    return (unsigned short)((x + 0x7fffu + ((x >> 16) & 1u)) >> 16);  // RNE
}
__device__ __forceinline__ float sigf(float x) {
    return 1.0f / (1.0f + __expf(-x));
}
__device__ __forceinline__ float tanh_fast(float x) {
    float ax = fabsf(x);
    float e  = __expf(-2.0f * ax);           // in (0,1], no overflow
    float t  = (1.0f - e) / (1.0f + e);
    return copysignf(t, x);
}

// ---- LLC-coherent (agent-scope) ops: sc0 sc1 bypass L1 + per-XCD L2.
// hb/flags are ONLY touched through these during lstm_rec -> no line of them
// ever lives in any L2 -> no acquire fences / buffer_inv needed anywhere.
__device__ __forceinline__ u32 poll_load_coh(const u32* p) {
    u32 v;
    asm volatile("global_load_dword %0, %1, off sc0 sc1\n\ts_waitcnt vmcnt(0)"
                 : "=v"(v) : "v"(p) : "memory");
    return v;
}
__device__ __forceinline__ void store_u32_coh(u32* p, u32 v) {
    asm volatile("global_store_dword %0, %1, off sc0 sc1" :: "v"(p), "v"(v) : "memory");
}

// ---------------- prep kernels ----------------

__global__ void cast_f32_bf16(const float* __restrict__ in,
                              unsigned short* __restrict__ out, int n) {
    int idx = (blockIdx.x * blockDim.x + threadIdx.x) * 4;
    if (idx + 3 < n) {
        float4 v = *(const float4*)(in + idx);
        ushort4 o;
        o.x = f2bf(v.x); o.y = f2bf(v.y); o.z = f2bf(v.z); o.w = f2bf(v.w);
        *(ushort4*)(out + idx) = o;
    }
}

__global__ void zero_u32(u32* __restrict__ p, int n) {
    int i = blockIdx.x * blockDim.x + threadIdx.x;
    if (i < n) p[i] = 0u;
}

// in: R x C fp32 (row-major) -> out: C x R bf16 (row-major transpose)
__global__ void transpose_cast(const float* __restrict__ in,
                               unsigned short* __restrict__ out, int R, int C) {
    __shared__ float tile[32][33];
    int c0 = blockIdx.x * 32, r0 = blockIdx.y * 32;
    int tx = threadIdx.x, ty = threadIdx.y;     // 32 x 8
#pragma unroll
    for (int i = 0; i < 4; ++i)
        tile[ty + i * 8][tx] = in[(size_t)(r0 + ty + i * 8) * C + c0 + tx];
    __syncthreads();
#pragma unroll
    for (int i = 0; i < 4; ++i)
        out[(size_t)(c0 + ty + i * 8) * R + r0 + tx] = f2bf(tile[tx][ty + i * 8]);
}

// ---------------- phase 1: Gp = perm(x @ Wx + b)  (bf16 MFMA, fp32 out) ----------------
// A: MROWS x DIM bf16 (x), BT: NGATE x DIM bf16 (WxT).
// Output written in recurrence-friendly permuted panels:
//   orig col co = g*1024 + hu  ->  panel wg = hu>>5, local col cp = g*32 + (hu&31)
//   Gp[((wg*MROWS)+row)*128 + cp]
__global__ __launch_bounds__(256) void gemm_xw(
    const unsigned short* __restrict__ A,
    const unsigned short* __restrict__ BT,
    const float* __restrict__ bias,
    float* __restrict__ Gp) {
    __shared__ unsigned short As[128 * 32];
    __shared__ unsigned short Bs[128 * 32];
    int tid  = threadIdx.x;
    int wave = tid >> 6, lane = tid & 63;
    int q = lane >> 4, c = lane & 15;
    int wm = wave >> 1, wn = wave & 1;
    int tm = blockIdx.y * 128, tn = blockIdx.x * 128;

    f32x4 acc[4][4] = {};

    const int srow0 = tid >> 2;           // 0..63
    const int srow1 = 64 + (tid >> 2);    // 64..127
    const int scol  = (tid & 3) * 8;      // bf16 elems

    u32x4 ra0, ra1, rb0, rb1;
    ra0 = *(const u32x4*)(A  + (size_t)(tm + srow0) * DIM + scol);
    ra1 = *(const u32x4*)(A  + (size_t)(tm + srow1) * DIM + scol);
    rb0 = *(const u32x4*)(BT + (size_t)(tn + srow0) * DIM + scol);
    rb1 = *(const u32x4*)(BT + (size_t)(tn + srow1) * DIM + scol);

    for (int kk = 0; kk < 32; ++kk) {
        __syncthreads();
        *(u32x4*)(As + srow0 * 32 + scol) = ra0;
        *(u32x4*)(As + srow1 * 32 + scol) = ra1;
        *(u32x4*)(Bs + srow0 * 32 + scol) = rb0;
        *(u32x4*)(Bs + srow1 * 32 + scol) = rb1;
        __syncthreads();
        if (kk < 31) {
            int ko = (kk + 1) * 32 + scol;
            ra0 = *(const u32x4*)(A  + (size_t)(tm + srow0) * DIM + ko);
            ra1 = *(const u32x4*)(A  + (size_t)(tm + srow1) * DIM + ko);
            rb0 = *(const u32x4*)(BT + (size_t)(tn + srow0) * DIM + ko);
            rb1 = *(const u32x4*)(BT + (size_t)(tn + srow1) * DIM + ko);
        }
        bf16x8 af[4], bfv[4];
#pragma unroll
        for (int i = 0; i < 4; ++i) {
            af[i]  = *(const bf16x8*)(As + (wm * 64 + i * 16 + c) * 32 + q * 8);
            bfv[i] = *(const bf16x8*)(Bs + (wn * 64 + i * 16 + c) * 32 + q * 8);
        }
#pragma unroll
        for (int i = 0; i < 4; ++i)
#pragma unroll
            for (int j = 0; j < 4; ++j)
                acc[i][j] = __builtin_amdgcn_mfma_f32_16x16x32_bf16(
                    af[i], bfv[j], acc[i][j], 0, 0, 0);
    }
    // epilogue: C/D layout col = lane&15, row = quad*4 + reg; permuted store
#pragma unroll
    for (int j = 0; j < 4; ++j) {
        int co = tn + wn * 64 + j * 16 + c;
        float bj = bias[co];
        int g = co >> 10, hu = co & 1023;
        int wgr = hu >> 5, u = hu & 31;
        int cp = g * 32 + u;
#pragma unroll
        for (int i = 0; i < 4; ++i) {
            int row0 = tm + wm * 64 + i * 16 + q * 4;
#pragma unroll
            for (int r = 0; r < 4; ++r)
                Gp[((size_t)wgr * MROWS + row0 + r) * 128 + cp] = acc[i][j][r] + bj;
        }
    }
}

// ---------------- phase 2: persistent recurrence ----------------
// 32 WGs x 512 threads (8 waves). WG wg owns hidden units [wg*32, wg*32+32) -> 128
// permuted gate cols. Wave wv: cg = wv&1 (2x 32-col tiles), ks = wv>>1 (K-split,
// 256 of 1024 = producers ks*8..ks*8+7). Wh fragments live in registers for all
// 128 steps. Per step: parallel poll (lane i watches producer ks*8+(i&7), one LLC
// round trip covers all 8), then ONE asm block issues all 16 h-loads (sc0sc1,
// imm offsets) + single vmcnt(0), then 32 MFMAs. h broadcast via sc0sc1
// write-through stores; flag raised right after vmcnt ack; out-store & G
// prefetch (slice t+1 -- consumed at step t+1) after the flag.
__global__ __launch_bounds__(512, 1) void lstm_rec(
    const unsigned short* __restrict__ WhT,   // NGATE x DIM bf16
    const float* __restrict__ Gp,             // permuted gates, 32 x 4096 x 128 fp32
    unsigned short* hb,                       // (T+1) x BATCH x HID bf16 (slot 0 unused)
    u32* flags,                               // (T+1) x NWGR
    float* __restrict__ out) {                // T x BATCH x HID fp32
    __shared__ float Gl[2][32][133];          // double-buffered G slice (pad 133: <=2-way)
    __shared__ float SlT[4][128][33];         // K-split partials, transposed (pad 33)
    const int wg = blockIdx.x, tid = threadIdx.x;
    const int wv = tid >> 6, lane = tid & 63;
    const int cg = wv & 1, ks = wv >> 1;
    const int ln = lane & 31, lh = lane >> 5;

    // ---- stage B-fragments (Wh) into registers, once ----
    bf16x8 br0[16], br1[16];
    {
        const unsigned short* w0 =
            WhT + (size_t)((cg * 2 + 0) * HID + wg * 32 + ln) * DIM + ks * 256 + lh * 8;
        const unsigned short* w1 =
            WhT + (size_t)((cg * 2 + 1) * HID + wg * 32 + ln) * DIM + ks * 256 + lh * 8;
#pragma unroll
        for (int kk = 0; kk < 16; ++kk) {
            br0[kk] = *(const bf16x8*)(w0 + kk * 16);
            br1[kk] = *(const bf16x8*)(w1 + kk * 16);
        }
    }

    // ---- G slice for t=0 into Gl[0] ----
    {
        const float* p = Gp + (size_t)wg * MROWS * 128 + tid * 8;
        f32x4 a = *(const f32x4*)p, b2 = *(const f32x4*)(p + 4);
        float* d = &Gl[0][tid >> 4][(tid & 15) * 8];
#pragma unroll
        for (int i = 0; i < 4; ++i) { d[i] = a[i]; d[4 + i] = b2[i]; }
    }
    __syncthreads();

    // epilogue mapping: thread = (batch, uu); owns units 2*uu, 2*uu+1
    const int batch = tid >> 4, uu = tid & 15;
    float cs0 = 0.f, cs1 = 0.f;
    f32x4 ga = {}, gb = {};

    for (int t = 0; t < T_STEPS; ++t) {
        const int cur = t & 1;

        // ---- K-phase: parallel poll + batched h-loads + 32 MFMAs ----
        f32x16 acc0 = {}, acc1 = {};
        if (t > 0) {
            const u32* fp = flags + (size_t)t * NWGR + ks * 8 + (lane & 7);
            while (poll_load_coh(fp) == 0u) {}   // divergent spin; converges when all 8 set

            const unsigned short* hbase = hb + (size_t)t * (BATCH * HID)
                                        + (size_t)ln * HID + ks * 256 + lh * 8;
            u32x4 h[16];
            asm volatile(
                "global_load_dwordx4 %0,  %16, off sc0 sc1\n\t"
                "global_load_dwordx4 %1,  %16, off offset:32 sc0 sc1\n\t"
                "global_load_dwordx4 %2,  %16, off offset:64 sc0 sc1\n\t"
                "global_load_dwordx4 %3,  %16, off offset:96 sc0 sc1\n\t"
                "global_load_dwordx4 %4,  %16, off offset:128 sc0 sc1\n\t"
                "global_load_dwordx4 %5,  %16, off offset:160 sc0 sc1\n\t"
                "global_load_dwordx4 %6,  %16, off offset:192 sc0 sc1\n\t"
                "global_load_dwordx4 %7,  %16, off offset:224 sc0 sc1\n\t"
                "global_load_dwordx4 %8,  %16, off offset:256 sc0 sc1\n\t"
                "global_load_dwordx4 %9,  %16, off offset:288 sc0 sc1\n\t"
                "global_load_dwordx4 %10, %16, off offset:320 sc0 sc1\n\t"
                "global_load_dwordx4 %11, %16, off offset:352 sc0 sc1\n\t"
                "global_load_dwordx4 %12, %16, off offset:384 sc0 sc1\n\t"
                "global_load_dwordx4 %13, %16, off offset:416 sc0 sc1\n\t"
                "global_load_dwordx4 %14, %16, off offset:448 sc0 sc1\n\t"
                "global_load_dwordx4 %15, %16, off offset:480 sc0 sc1\n\t"
                "s_waitcnt vmcnt(0)"
                : "=&v"(h[0]),  "=&v"(h[1]),  "=&v"(h[2]),  "=&v"(h[3]),
                  "=&v"(h[4]),  "=&v"(h[5]),  "=&v"(h[6]),  "=&v"(h[7]),
                  "=&v"(h[8]),  "=&v"(h[9]),  "=&v"(h[10]), "=&v"(h[11]),
                  "=&v"(h[12]), "=&v"(h[13]), "=&v"(h[14]), "=&v"(h[15])
                : "v"(hbase)
                : "memory");

#pragma unroll
            for (int jj = 0; jj < 8; ++jj) {
                bf16x8 a0 = __builtin_bit_cast(bf16x8, h[2 * jj]);
                bf16x8 a1 = __builtin_bit_cast(bf16x8, h[2 * jj + 1]);
                acc0 = __builtin_amdgcn_mfma_f32_32x32x16_bf16(a0, br0[jj * 2],     acc0, 0, 0, 0);
                acc1 = __builtin_amdgcn_mfma_f32_32x32x16_bf16(a0, br1[jj * 2],     acc1, 0, 0, 0);
                acc0 = __builtin_amdgcn_mfma_f32_32x32x16_bf16(a1, br0[jj * 2 + 1], acc0, 0, 0, 0);
                acc1 = __builtin_amdgcn_mfma_f32_32x32x16_bf16(a1, br1[jj * 2 + 1], acc1, 0, 0, 0);
            }
        }

        // ---- K-split partials into LDS (scalar, conflict-free at pad 33) ----
        // C layout 32x32: col = lane&31, row = (reg&3) + 8*(reg>>2) + 4*(lane>>5)
#pragma unroll
        for (int rg = 0; rg < 4; ++rg)
#pragma unroll
            for (int rr = 0; rr < 4; ++rr) {
                SlT[ks][cg * 64 + ln]     [rg * 8 + lh * 4 + rr] = acc0[rg * 4 + rr];
                SlT[ks][cg * 64 + 32 + ln][rg * 8 + lh * 4 + rr] = acc1[rg * 4 + rr];
            }
        if (t > 0) {   // Gl[cur] for t==0 was pre-filled; ga/gb holds slice t
            float* d = &Gl[cur][tid >> 4][(tid & 15) * 8];
#pragma unroll
            for (int i = 0; i < 4; ++i) { d[i] = ga[i]; d[4 + i] = gb[i]; }
        }
        __syncthreads();

        // ---- epilogue: units u0 = 2*uu, u1 = 2*uu+1 of batch ----
        float gv0[4], gv1[4];
#pragma unroll
        for (int g = 0; g < 4; ++g) {
            const int c0 = g * 32 + 2 * uu, c1 = c0 + 1;
            gv0[g] = Gl[cur][batch][c0] + SlT[0][c0][batch] + SlT[1][c0][batch]
                                        + SlT[2][c0][batch] + SlT[3][c0][batch];
            gv1[g] = Gl[cur][batch][c1] + SlT[0][c1][batch] + SlT[1][c1][batch]
                                        + SlT[2][c1][batch] + SlT[3][c1][batch];
        }
        float cn0 = sigf(gv0[1]) * cs0 + sigf(gv0[0]) * tanh_fast(gv0[2]);
        float cn1 = sigf(gv1[1]) * cs1 + sigf(gv1[0]) * tanh_fast(gv1[2]);
        cs0 = cn0; cs1 = cn1;
        float hv0 = sigf(gv0[3]) * tanh_fast(cn0);
        float hv1 = sigf(gv1[3]) * tanh_fast(cn1);
        u32 packed = (u32)f2bf(hv0) | ((u32)f2bf(hv1) << 16);
        store_u32_coh((u32*)(hb + (size_t)(t + 1) * (BATCH * HID)
                                + (size_t)batch * HID + wg * 32 + 2 * uu), packed);

        // all h stores of every thread LLC-ack'd before flag goes up
        asm volatile("s_waitcnt vmcnt(0)" ::: "memory");
        __syncthreads();
        if (tid == 0)
            store_u32_coh(flags + (size_t)(t + 1) * NWGR + wg, 1u);

        // off the critical path: G prefetch for step t+1 (consumed at t+1's Gl
        // write -- NOT t+2: that was R3's off-by-one) + out-store
        if (t + 1 < T_STEPS) {
            const float* p = Gp + ((size_t)wg * MROWS + (size_t)(t + 1) * 32) * 128 + tid * 8;
            ga = *(const f32x4*)p; gb = *(const f32x4*)(p + 4);
        }
        *(float2*)(out + ((size_t)t * BATCH + batch) * HID + wg * 32 + 2 * uu) =
            make_float2(hv0, hv1);
    }
}

// ---------------- launch ----------------

extern "C" void kernel_launch(void* const* d_in, const int* in_sizes, int n_in,
                              void* d_out, int out_size, void* d_ws, size_t ws_size,
                              hipStream_t stream) {
    const float* x  = (const float*)d_in[0];   // T*B*D
    const float* Wx = (const float*)d_in[1];   // D x 4H
    const float* Wh = (const float*)d_in[2];   // H x 4H
    const float* b  = (const float*)d_in[3];   // 4H
    float* out = (float*)d_out;

    // workspace layout (bytes)
    char* ws = (char*)d_ws;
    const size_t OFF_XBF  = 0;                       // 8 MB  (4096x1024 bf16)
    const size_t OFF_WXT  = 8ull  << 20;             // 8 MB  (4096x1024 bf16)
    const size_t OFF_WHT  = 16ull << 20;             // 8 MB  (4096x1024 bf16)
    const size_t OFF_G    = 24ull << 20;             // 64 MB (32x4096x128 fp32 permuted)
    const size_t OFF_HB   = 88ull << 20;             // 129 * 64 KB = 8.0625 MB
    const size_t OFF_FLAG = 97ull << 20;             // 129 * 32 * 4 B
    const size_t NEEDED   = OFF_FLAG + (size_t)(T_STEPS + 1) * NWGR * 4;
    if (ws_size < NEEDED) return;  // loud failure (output stays poisoned)

    unsigned short* xbf = (unsigned short*)(ws + OFF_XBF);
    unsigned short* WxT = (unsigned short*)(ws + OFF_WXT);
    unsigned short* WhT = (unsigned short*)(ws + OFF_WHT);
    float*          Gp  = (float*)(ws + OFF_G);
    unsigned short* hb  = (unsigned short*)(ws + OFF_HB);
    u32*            fl  = (u32*)(ws + OFF_FLAG);

    // prep
    cast_f32_bf16<<<(MROWS * DIM / 4 + 255) / 256, 256, 0, stream>>>(x, xbf, MROWS * DIM);
    int nflags = (T_STEPS + 1) * NWGR;
    zero_u32<<<(nflags + 255) / 256, 256, 0, stream>>>(fl, nflags);
    dim3 tb(32, 8);
    transpose_cast<<<dim3(NGATE / 32, DIM / 32), tb, 0, stream>>>(Wx, WxT, DIM, NGATE);
    transpose_cast<<<dim3(NGATE / 32, HID / 32), tb, 0, stream>>>(Wh, WhT, HID, NGATE);

    // phase 1: all-timestep input GEMM (permuted output)
    gemm_xw<<<dim3(NGATE / 128, MROWS / 128), 256, 0, stream>>>(xbf, WxT, b, Gp);

    // phase 2: persistent recurrence
    lstm_rec<<<NWGR, 512, 0, stream>>>(WhT, Gp, hb, fl, out);
}

// Round 5
// 981.581 us; speedup vs baseline: 2.2992x; 1.0582x over previous
//
#include <hip/hip_runtime.h>
#include <hip/hip_bf16.h>
#include <stdint.h>

// Problem: T=128, B=32, D=1024, H=1024 LSTM unroll, fp32 in/out.
#define T_STEPS 128
#define BATCH   32
#define DIM     1024
#define HID     1024
#define NGATE   4096            // 4*H
#define MROWS   4096            // T*B
#define NWGR    32              // persistent recurrence workgroups
#define FSTRIDE 32              // u32s per flag (one 128B line each)

typedef unsigned int u32;
typedef __attribute__((ext_vector_type(8)))  __bf16 bf16x8;
typedef __attribute__((ext_vector_type(4)))  float  f32x4;
typedef __attribute__((ext_vector_type(16))) float  f32x16;
typedef __attribute__((ext_vector_type(4)))  u32    u32x4;

__device__ __forceinline__ unsigned short f2bf(float f) {
    u32 x = __float_as_uint(f);
    return (unsigned short)((x + 0x7fffu + ((x >> 16) & 1u)) >> 16);  // RNE
}
__device__ __forceinline__ float sigf(float x) {
    return 1.0f / (1.0f + __expf(-x));
}
__device__ __forceinline__ float tanh_fast(float x) {
    float ax = fabsf(x);
    float e  = __expf(-2.0f * ax);           // in (0,1], no overflow
    float t  = (1.0f - e) / (1.0f + e);
    return copysignf(t, x);
}

// ---- DEVICE-scope (agent) ops: sc1 only (gfx94x: SC1:SC0 = 10 = device).
// Bypasses L1 + per-XCD L2, served by the memory-side Infinity Cache.
// (R2-R4 used sc0 sc1 = SYSTEM scope -- stronger and slower than needed.)
// hb/flags are ONLY touched through these during lstm_rec -> no line of them
// ever lives in any L2 -> no acquire fences / buffer_inv needed anywhere.
__device__ __forceinline__ u32 poll_load_coh(const u32* p) {
    u32 v;
    asm volatile("global_load_dword %0, %1, off sc1\n\ts_waitcnt vmcnt(0)"
                 : "=v"(v) : "v"(p) : "memory");
    return v;
}
__device__ __forceinline__ void store_u32_coh(u32* p, u32 v) {
    asm volatile("global_store_dword %0, %1, off sc1" :: "v"(p), "v"(v) : "memory");
}

// ---------------- prep kernels ----------------

__global__ void cast_f32_bf16(const float* __restrict__ in,
                              unsigned short* __restrict__ out, int n) {
    int idx = (blockIdx.x * blockDim.x + threadIdx.x) * 4;
    if (idx + 3 < n) {
        float4 v = *(const float4*)(in + idx);
        ushort4 o;
        o.x = f2bf(v.x); o.y = f2bf(v.y); o.z = f2bf(v.z); o.w = f2bf(v.w);
        *(ushort4*)(out + idx) = o;
    }
}

__global__ void zero_u32(u32* __restrict__ p, int n) {
    int i = blockIdx.x * blockDim.x + threadIdx.x;
    if (i < n) p[i] = 0u;
}

// in: R x C fp32 (row-major) -> out: C x R bf16 (row-major transpose)
__global__ void transpose_cast(const float* __restrict__ in,
                               unsigned short* __restrict__ out, int R, int C) {
    __shared__ float tile[32][33];
    int c0 = blockIdx.x * 32, r0 = blockIdx.y * 32;
    int tx = threadIdx.x, ty = threadIdx.y;     // 32 x 8
#pragma unroll
    for (int i = 0; i < 4; ++i)
        tile[ty + i * 8][tx] = in[(size_t)(r0 + ty + i * 8) * C + c0 + tx];
    __syncthreads();
#pragma unroll
    for (int i = 0; i < 4; ++i)
        out[(size_t)(c0 + ty + i * 8) * R + r0 + tx] = f2bf(tile[tx][ty + i * 8]);
}

// ---------------- phase 1: Gp = perm(x @ Wx + b)  (bf16 MFMA, fp32 out) ----------------
// A: MROWS x DIM bf16 (x), BT: NGATE x DIM bf16 (WxT).
// Output written in recurrence-friendly permuted panels:
//   orig col co = g*1024 + hu  ->  panel wg = hu>>5, local col cp = g*32 + (hu&31)
//   Gp[((wg*MROWS)+row)*128 + cp]
__global__ __launch_bounds__(256) void gemm_xw(
    const unsigned short* __restrict__ A,
    const unsigned short* __restrict__ BT,
    const float* __restrict__ bias,
    float* __restrict__ Gp) {
    __shared__ unsigned short As[128 * 32];
    __shared__ unsigned short Bs[128 * 32];
    int tid  = threadIdx.x;
    int wave = tid >> 6, lane = tid & 63;
    int q = lane >> 4, c = lane & 15;
    int wm = wave >> 1, wn = wave & 1;
    int tm = blockIdx.y * 128, tn = blockIdx.x * 128;

    f32x4 acc[4][4] = {};

    const int srow0 = tid >> 2;           // 0..63
    const int srow1 = 64 + (tid >> 2);    // 64..127
    const int scol  = (tid & 3) * 8;      // bf16 elems

    u32x4 ra0, ra1, rb0, rb1;
    ra0 = *(const u32x4*)(A  + (size_t)(tm + srow0) * DIM + scol);
    ra1 = *(const u32x4*)(A  + (size_t)(tm + srow1) * DIM + scol);
    rb0 = *(const u32x4*)(BT + (size_t)(tn + srow0) * DIM + scol);
    rb1 = *(const u32x4*)(BT + (size_t)(tn + srow1) * DIM + scol);

    for (int kk = 0; kk < 32; ++kk) {
        __syncthreads();
        *(u32x4*)(As + srow0 * 32 + scol) = ra0;
        *(u32x4*)(As + srow1 * 32 + scol) = ra1;
        *(u32x4*)(Bs + srow0 * 32 + scol) = rb0;
        *(u32x4*)(Bs + srow1 * 32 + scol) = rb1;
        __syncthreads();
        if (kk < 31) {
            int ko = (kk + 1) * 32 + scol;
            ra0 = *(const u32x4*)(A  + (size_t)(tm + srow0) * DIM + ko);
            ra1 = *(const u32x4*)(A  + (size_t)(tm + srow1) * DIM + ko);
            rb0 = *(const u32x4*)(BT + (size_t)(tn + srow0) * DIM + ko);
            rb1 = *(const u32x4*)(BT + (size_t)(tn + srow1) * DIM + ko);
        }
        bf16x8 af[4], bfv[4];
#pragma unroll
        for (int i = 0; i < 4; ++i) {
            af[i]  = *(const bf16x8*)(As + (wm * 64 + i * 16 + c) * 32 + q * 8);
            bfv[i] = *(const bf16x8*)(Bs + (wn * 64 + i * 16 + c) * 32 + q * 8);
        }
#pragma unroll
        for (int i = 0; i < 4; ++i)
#pragma unroll
            for (int j = 0; j < 4; ++j)
                acc[i][j] = __builtin_amdgcn_mfma_f32_16x16x32_bf16(
                    af[i], bfv[j], acc[i][j], 0, 0, 0);
    }
    // epilogue: C/D layout col = lane&15, row = quad*4 + reg; permuted store
#pragma unroll
    for (int j = 0; j < 4; ++j) {
        int co = tn + wn * 64 + j * 16 + c;
        float bj = bias[co];
        int g = co >> 10, hu = co & 1023;
        int wgr = hu >> 5, u = hu & 31;
        int cp = g * 32 + u;
#pragma unroll
        for (int i = 0; i < 4; ++i) {
            int row0 = tm + wm * 64 + i * 16 + q * 4;
#pragma unroll
            for (int r = 0; r < 4; ++r)
                Gp[((size_t)wgr * MROWS + row0 + r) * 128 + cp] = acc[i][j][r] + bj;
        }
    }
}

// ---------------- phase 2: persistent recurrence ----------------
// 32 WGs x 512 threads (8 waves). WG wg owns hidden units [wg*32, wg*32+32) -> 128
// permuted gate cols. Wave wv: cg = wv&1 (2x 32-col tiles), ks = wv>>1 (K-split,
// 256 of 1024 = producers ks*8..ks*8+7). Wh fragments live in registers for all
// 128 steps. Flags: ONE location per producer, its own 128B line, monotone
// step-tag (producer stores t+1 after step t; consumer at step t polls >= t --
// '>=' is stall-proof if a producer runs a step ahead). Per step: parallel poll
// (lane i watches producer ks*8+(i&7) -> 8 distinct lines per wave), then ONE
// asm block issues all 16 h-loads (device scope) + single vmcnt(0), then 32
// MFMAs. h broadcast via sc1 write-through stores; flag raised right after
// vmcnt ack; out-store & G prefetch after the flag.
__global__ __launch_bounds__(512, 1) void lstm_rec(
    const unsigned short* __restrict__ WhT,   // NGATE x DIM bf16
    const float* __restrict__ Gp,             // permuted gates, 32 x 4096 x 128 fp32
    unsigned short* hb,                       // (T+1) x BATCH x HID bf16 (slot 0 unused)
    u32* flags,                               // NWGR flags, stride FSTRIDE u32
    float* __restrict__ out) {                // T x BATCH x HID fp32
    __shared__ float Gl[2][32][133];          // double-buffered G slice (pad 133)
    __shared__ float SlT[4][128][33];         // K-split partials, transposed (pad 33)
    const int wg = blockIdx.x, tid = threadIdx.x;
    const int wv = tid >> 6, lane = tid & 63;
    const int cg = wv & 1, ks = wv >> 1;
    const int ln = lane & 31, lh = lane >> 5;

    // ---- stage B-fragments (Wh) into registers, once ----
    bf16x8 br0[16], br1[16];
    {
        const unsigned short* w0 =
            WhT + (size_t)((cg * 2 + 0) * HID + wg * 32 + ln) * DIM + ks * 256 + lh * 8;
        const unsigned short* w1 =
            WhT + (size_t)((cg * 2 + 1) * HID + wg * 32 + ln) * DIM + ks * 256 + lh * 8;
#pragma unroll
        for (int kk = 0; kk < 16; ++kk) {
            br0[kk] = *(const bf16x8*)(w0 + kk * 16);
            br1[kk] = *(const bf16x8*)(w1 + kk * 16);
        }
    }

    // ---- G slice for t=0 into Gl[0] ----
    {
        const float* p = Gp + (size_t)wg * MROWS * 128 + tid * 8;
        f32x4 a = *(const f32x4*)p, b2 = *(const f32x4*)(p + 4);
        float* d = &Gl[0][tid >> 4][(tid & 15) * 8];
#pragma unroll
        for (int i = 0; i < 4; ++i) { d[i] = a[i]; d[4 + i] = b2[i]; }
    }
    __syncthreads();

    // epilogue mapping: thread = (batch, uu); owns units 2*uu, 2*uu+1
    const int batch = tid >> 4, uu = tid & 15;
    float cs0 = 0.f, cs1 = 0.f;
    f32x4 ga = {}, gb = {};

    for (int t = 0; t < T_STEPS; ++t) {
        const int cur = t & 1;

        // ---- K-phase: parallel poll + batched h-loads + 32 MFMAs ----
        f32x16 acc0 = {}, acc1 = {};
        if (t > 0) {
            const u32* fp = flags + (size_t)(ks * 8 + (lane & 7)) * FSTRIDE;
            while (poll_load_coh(fp) < (u32)t) {}   // divergent spin, monotone tag

            const unsigned short* hbase = hb + (size_t)t * (BATCH * HID)
                                        + (size_t)ln * HID + ks * 256 + lh * 8;
            u32x4 h[16];
            asm volatile(
                "global_load_dwordx4 %0,  %16, off sc1\n\t"
                "global_load_dwordx4 %1,  %16, off offset:32 sc1\n\t"
                "global_load_dwordx4 %2,  %16, off offset:64 sc1\n\t"
                "global_load_dwordx4 %3,  %16, off offset:96 sc1\n\t"
                "global_load_dwordx4 %4,  %16, off offset:128 sc1\n\t"
                "global_load_dwordx4 %5,  %16, off offset:160 sc1\n\t"
                "global_load_dwordx4 %6,  %16, off offset:192 sc1\n\t"
                "global_load_dwordx4 %7,  %16, off offset:224 sc1\n\t"
                "global_load_dwordx4 %8,  %16, off offset:256 sc1\n\t"
                "global_load_dwordx4 %9,  %16, off offset:288 sc1\n\t"
                "global_load_dwordx4 %10, %16, off offset:320 sc1\n\t"
                "global_load_dwordx4 %11, %16, off offset:352 sc1\n\t"
                "global_load_dwordx4 %12, %16, off offset:384 sc1\n\t"
                "global_load_dwordx4 %13, %16, off offset:416 sc1\n\t"
                "global_load_dwordx4 %14, %16, off offset:448 sc1\n\t"
                "global_load_dwordx4 %15, %16, off offset:480 sc1\n\t"
                "s_waitcnt vmcnt(0)"
                : "=&v"(h[0]),  "=&v"(h[1]),  "=&v"(h[2]),  "=&v"(h[3]),
                  "=&v"(h[4]),  "=&v"(h[5]),  "=&v"(h[6]),  "=&v"(h[7]),
                  "=&v"(h[8]),  "=&v"(h[9]),  "=&v"(h[10]), "=&v"(h[11]),
                  "=&v"(h[12]), "=&v"(h[13]), "=&v"(h[14]), "=&v"(h[15])
                : "v"(hbase)
                : "memory");

#pragma unroll
            for (int jj = 0; jj < 8; ++jj) {
                bf16x8 a0 = __builtin_bit_cast(bf16x8, h[2 * jj]);
                bf16x8 a1 = __builtin_bit_cast(bf16x8, h[2 * jj + 1]);
                acc0 = __builtin_amdgcn_mfma_f32_32x32x16_bf16(a0, br0[jj * 2],     acc0, 0, 0, 0);
                acc1 = __builtin_amdgcn_mfma_f32_32x32x16_bf16(a0, br1[jj * 2],     acc1, 0, 0, 0);
                acc0 = __builtin_amdgcn_mfma_f32_32x32x16_bf16(a1, br0[jj * 2 + 1], acc0, 0, 0, 0);
                acc1 = __builtin_amdgcn_mfma_f32_32x32x16_bf16(a1, br1[jj * 2 + 1], acc1, 0, 0, 0);
            }
        }

        // ---- K-split partials into LDS (scalar, conflict-free at pad 33) ----
        // C layout 32x32: col = lane&31, row = (reg&3) + 8*(reg>>2) + 4*(lane>>5)
#pragma unroll
        for (int rg = 0; rg < 4; ++rg)
#pragma unroll
            for (int rr = 0; rr < 4; ++rr) {
                SlT[ks][cg * 64 + ln]     [rg * 8 + lh * 4 + rr] = acc0[rg * 4 + rr];
                SlT[ks][cg * 64 + 32 + ln][rg * 8 + lh * 4 + rr] = acc1[rg * 4 + rr];
            }
        if (t > 0) {   // Gl[cur] for t==0 was pre-filled; ga/gb holds slice t
            float* d = &Gl[cur][tid >> 4][(tid & 15) * 8];
#pragma unroll
            for (int i = 0; i < 4; ++i) { d[i] = ga[i]; d[4 + i] = gb[i]; }
        }
        __syncthreads();

        // ---- epilogue: units u0 = 2*uu, u1 = 2*uu+1 of batch ----
        float gv0[4], gv1[4];
#pragma unroll
        for (int g = 0; g < 4; ++g) {
            const int c0 = g * 32 + 2 * uu, c1 = c0 + 1;
            gv0[g] = Gl[cur][batch][c0] + SlT[0][c0][batch] + SlT[1][c0][batch]
                                        + SlT[2][c0][batch] + SlT[3][c0][batch];
            gv1[g] = Gl[cur][batch][c1] + SlT[0][c1][batch] + SlT[1][c1][batch]
                                        + SlT[2][c1][batch] + SlT[3][c1][batch];
        }
        float cn0 = sigf(gv0[1]) * cs0 + sigf(gv0[0]) * tanh_fast(gv0[2]);
        float cn1 = sigf(gv1[1]) * cs1 + sigf(gv1[0]) * tanh_fast(gv1[2]);
        cs0 = cn0; cs1 = cn1;
        float hv0 = sigf(gv0[3]) * tanh_fast(cn0);
        float hv1 = sigf(gv1[3]) * tanh_fast(cn1);
        u32 packed = (u32)f2bf(hv0) | ((u32)f2bf(hv1) << 16);
        store_u32_coh((u32*)(hb + (size_t)(t + 1) * (BATCH * HID)
                                + (size_t)batch * HID + wg * 32 + 2 * uu), packed);

        // all h stores of every thread ack'd at the coherence point, then flag
        asm volatile("s_waitcnt vmcnt(0)" ::: "memory");
        __syncthreads();
        if (tid == 0)
            store_u32_coh(flags + (size_t)wg * FSTRIDE, (u32)(t + 1));

        // off the critical path: G prefetch for step t+1 + out-store
        if (t + 1 < T_STEPS) {
            const float* p = Gp + ((size_t)wg * MROWS + (size_t)(t + 1) * 32) * 128 + tid * 8;
            ga = *(const f32x4*)p; gb = *(const f32x4*)(p + 4);
        }
        *(float2*)(out + ((size_t)t * BATCH + batch) * HID + wg * 32 + 2 * uu) =
            make_float2(hv0, hv1);
    }
}

// ---------------- launch ----------------

extern "C" void kernel_launch(void* const* d_in, const int* in_sizes, int n_in,
                              void* d_out, int out_size, void* d_ws, size_t ws_size,
                              hipStream_t stream) {
    const float* x  = (const float*)d_in[0];   // T*B*D
    const float* Wx = (const float*)d_in[1];   // D x 4H
    const float* Wh = (const float*)d_in[2];   // H x 4H
    const float* b  = (const float*)d_in[3];   // 4H
    float* out = (float*)d_out;

    // workspace layout (bytes)
    char* ws = (char*)d_ws;
    const size_t OFF_XBF  = 0;                       // 8 MB  (4096x1024 bf16)
    const size_t OFF_WXT  = 8ull  << 20;             // 8 MB  (4096x1024 bf16)
    const size_t OFF_WHT  = 16ull << 20;             // 8 MB  (4096x1024 bf16)
    const size_t OFF_G    = 24ull << 20;             // 64 MB (32x4096x128 fp32 permuted)
    const size_t OFF_HB   = 88ull << 20;             // 129 * 64 KB = 8.0625 MB
    const size_t OFF_FLAG = 97ull << 20;             // 32 flags x 128 B
    const size_t NEEDED   = OFF_FLAG + (size_t)NWGR * FSTRIDE * 4;
    if (ws_size < NEEDED) return;  // loud failure (output stays poisoned)

    unsigned short* xbf = (unsigned short*)(ws + OFF_XBF);
    unsigned short* WxT = (unsigned short*)(ws + OFF_WXT);
    unsigned short* WhT = (unsigned short*)(ws + OFF_WHT);
    float*          Gp  = (float*)(ws + OFF_G);
    unsigned short* hb  = (unsigned short*)(ws + OFF_HB);
    u32*            fl  = (u32*)(ws + OFF_FLAG);

    // prep
    cast_f32_bf16<<<(MROWS * DIM / 4 + 255) / 256, 256, 0, stream>>>(x, xbf, MROWS * DIM);
    int nflags = NWGR * FSTRIDE;
    zero_u32<<<(nflags + 255) / 256, 256, 0, stream>>>(fl, nflags);
    dim3 tb(32, 8);
    transpose_cast<<<dim3(NGATE / 32, DIM / 32), tb, 0, stream>>>(Wx, WxT, DIM, NGATE);
    transpose_cast<<<dim3(NGATE / 32, HID / 32), tb, 0, stream>>>(Wh, WhT, HID, NGATE);

    // phase 1: all-timestep input GEMM (permuted output)
    gemm_xw<<<dim3(NGATE / 128, MROWS / 128), 256, 0, stream>>>(xbf, WxT, b, Gp);

    // phase 2: persistent recurrence
    lstm_rec<<<NWGR, 512, 0, stream>>>(WhT, Gp, hb, fl, out);
}